// Round 1
// baseline (1582.414 us; speedup 1.0000x reference)
//
#include <hip/hip_runtime.h>
#include <math.h>

// ---------------------------------------------------------------------------
// StandardMoELayer on MI355X.
// Precision strategy: everything upstream of the router (QKV, attention,
// out-proj, LN1) must be fp32-accurate or top-2 routing flips vs the numpy
// reference (each flip => ~0.8 absmax >> 0.108 threshold). We use fp16x3
// split-MFMA (hi/lo decomposition, power-of-2 scaled so lo stays normal) for
// fp32-class GEMM/attention precision at MFMA rates. Post-router MoE FFN is
// values-only => plain bf16 MFMA.
// ---------------------------------------------------------------------------

typedef __attribute__((ext_vector_type(4))) float f32x4;
typedef __attribute__((ext_vector_type(8))) _Float16 f16x8;
typedef __attribute__((ext_vector_type(4))) _Float16 f16x4;
typedef __attribute__((ext_vector_type(8))) short bf16x8;

#define DEVI static __device__ __forceinline__

DEVI unsigned short f2bf(float f) {
  unsigned int u = __builtin_bit_cast(unsigned int, f);
  return (unsigned short)((u + 0x7fffu + ((u >> 16) & 1u)) >> 16);
}

DEVI f32x4 fzero4() { f32x4 z; z[0]=0.f; z[1]=0.f; z[2]=0.f; z[3]=0.f; return z; }

// split v into fp16 hi + fp16 lo (v ~ hi + lo, error ~2^-24 rel w/ scaling)
DEVI void splitf16(float v, _Float16* hi, _Float16* lo) {
  _Float16 h = (_Float16)v;
  *hi = h;
  *lo = (_Float16)(v - (float)h);
}

// ---------------------------------------------------------------------------
// elementwise prep kernels
// ---------------------------------------------------------------------------
__global__ void split_kernel(const float* __restrict__ in,
                             _Float16* __restrict__ oh, _Float16* __restrict__ ol,
                             float scale, int n4) {
  int i = blockIdx.x * 256 + threadIdx.x;
  if (i >= n4) return;
  float4 v = ((const float4*)in)[i];
  f16x4 hv, lv; _Float16 hh, ll;
  splitf16(v.x * scale, &hh, &ll); hv[0]=hh; lv[0]=ll;
  splitf16(v.y * scale, &hh, &ll); hv[1]=hh; lv[1]=ll;
  splitf16(v.z * scale, &hh, &ll); hv[2]=hh; lv[2]=ll;
  splitf16(v.w * scale, &hh, &ll); hv[3]=hh; lv[3]=ll;
  ((f16x4*)oh)[i] = hv;
  ((f16x4*)ol)[i] = lv;
}

__global__ void castbf_kernel(const float* __restrict__ in,
                              unsigned short* __restrict__ o, int n4) {
  int i = blockIdx.x * 256 + threadIdx.x;
  if (i >= n4) return;
  float4 v = ((const float4*)in)[i];
  ushort4 r;
  r.x = f2bf(v.x); r.y = f2bf(v.y); r.z = f2bf(v.z); r.w = f2bf(v.w);
  ((ushort4*)o)[i] = r;
}

// ---------------------------------------------------------------------------
// fp16x3 GEMM: C[M,N] = A[M,K] * W[N,K]^T  (A scaled 2^11, W scaled 2^10)
// 128x128 tile, BK=32, 4 waves (2x2 of 64x64), mfma_f32_16x16x32_f16 x3.
// EPI 0: +bias, split-store Q([bh][t][d]), K([bh][t][d]), V transposed ([bh][d][t])
// EPI 1: +bias +res -> fp32 out
// ---------------------------------------------------------------------------
template<int EPI>
__global__ __launch_bounds__(256) void gemm_f16x3(
    const _Float16* __restrict__ Ah, const _Float16* __restrict__ Al,
    const _Float16* __restrict__ Bh, const _Float16* __restrict__ Bl,
    const float* __restrict__ bias, int N, int K,
    float* __restrict__ out_f, const float* __restrict__ res,
    _Float16* __restrict__ Qh, _Float16* __restrict__ Ql,
    _Float16* __restrict__ Kh, _Float16* __restrict__ Kl,
    _Float16* __restrict__ Vh, _Float16* __restrict__ Vl) {
  __shared__ _Float16 AsH[128][40], AsL[128][40], BsH[128][40], BsL[128][40];
  const int tid = threadIdx.x;
  const int lane = tid & 63, wave = tid >> 6;
  const int wm = wave >> 1, wn = wave & 1;
  const int qr = lane & 15, lq = lane >> 4;
  const int rowBase = blockIdx.y * 128, colBase = blockIdx.x * 128;

  const int r0 = tid >> 2;          // 0..63
  const int k8 = (tid & 3) * 8;     // 0,8,16,24
  const _Float16 *pAh[2], *pAl[2], *pBh[2], *pBl[2];
#pragma unroll
  for (int j = 0; j < 2; ++j) {
    size_t ar = (size_t)(rowBase + r0 + 64*j) * K + k8;
    size_t bc = (size_t)(colBase + r0 + 64*j) * K + k8;
    pAh[j] = Ah + ar; pAl[j] = Al + ar;
    pBh[j] = Bh + bc; pBl[j] = Bl + bc;
  }
  f32x4 acc[4][4];
#pragma unroll
  for (int m = 0; m < 4; ++m)
#pragma unroll
    for (int n = 0; n < 4; ++n) acc[m][n] = fzero4();

  const int NT = K >> 5;
  uint4 sAh[2], sAl[2], sBh[2], sBl[2];
#pragma unroll
  for (int j = 0; j < 2; ++j) {
    sAh[j] = *(const uint4*)pAh[j]; sAl[j] = *(const uint4*)pAl[j];
    sBh[j] = *(const uint4*)pBh[j]; sBl[j] = *(const uint4*)pBl[j];
  }
  for (int kt = 0; kt < NT; ++kt) {
    __syncthreads();
#pragma unroll
    for (int j = 0; j < 2; ++j) {
      int rr = r0 + 64*j;
      *(uint4*)&AsH[rr][k8] = sAh[j];
      *(uint4*)&AsL[rr][k8] = sAl[j];
      *(uint4*)&BsH[rr][k8] = sBh[j];
      *(uint4*)&BsL[rr][k8] = sBl[j];
    }
    __syncthreads();
    if (kt + 1 < NT) {
      int off = (kt + 1) * 32;
#pragma unroll
      for (int j = 0; j < 2; ++j) {
        sAh[j] = *(const uint4*)(pAh[j] + off);
        sAl[j] = *(const uint4*)(pAl[j] + off);
        sBh[j] = *(const uint4*)(pBh[j] + off);
        sBl[j] = *(const uint4*)(pBl[j] + off);
      }
    }
    f16x8 ah[4], al[4], bh[4], bl[4];
#pragma unroll
    for (int mt = 0; mt < 4; ++mt) {
      ah[mt] = *(const f16x8*)&AsH[wm*64 + mt*16 + qr][lq*8];
      al[mt] = *(const f16x8*)&AsL[wm*64 + mt*16 + qr][lq*8];
    }
#pragma unroll
    for (int nt = 0; nt < 4; ++nt) {
      bh[nt] = *(const f16x8*)&BsH[wn*64 + nt*16 + qr][lq*8];
      bl[nt] = *(const f16x8*)&BsL[wn*64 + nt*16 + qr][lq*8];
    }
#pragma unroll
    for (int mt = 0; mt < 4; ++mt)
#pragma unroll
      for (int nt = 0; nt < 4; ++nt) {
        f32x4 c = acc[mt][nt];
        c = __builtin_amdgcn_mfma_f32_16x16x32_f16(ah[mt], bh[nt], c, 0, 0, 0);
        c = __builtin_amdgcn_mfma_f32_16x16x32_f16(ah[mt], bl[nt], c, 0, 0, 0);
        c = __builtin_amdgcn_mfma_f32_16x16x32_f16(al[mt], bh[nt], c, 0, 0, 0);
        acc[mt][nt] = c;
      }
  }
  const float inv21 = 1.0f / 2097152.0f;  // 2^-21 (2^11 * 2^10 scales)
#pragma unroll
  for (int mt = 0; mt < 4; ++mt)
#pragma unroll
    for (int nt = 0; nt < 4; ++nt)
#pragma unroll
      for (int r = 0; r < 4; ++r) {
        int grow = rowBase + wm*64 + mt*16 + lq*4 + r;
        int col  = colBase + wn*64 + nt*16 + qr;
        float v = acc[mt][nt][r] * inv21 + bias[col];
        if (EPI == 0) {
          int sect = col >> 10, c = col & 1023;
          int hh2 = c >> 6, dd = c & 63;
          int t = grow >> 3, b = grow & 7;
          int bh_ = b * 16 + hh2;
          _Float16 h_, l_;
          splitf16(v * 2048.0f, &h_, &l_);
          if (sect == 0) {
            size_t dst = ((size_t)bh_ * 1024 + t) * 64 + dd;
            Qh[dst] = h_; Ql[dst] = l_;
          } else if (sect == 1) {
            size_t dst = ((size_t)bh_ * 1024 + t) * 64 + dd;
            Kh[dst] = h_; Kl[dst] = l_;
          } else {
            size_t dst = ((size_t)bh_ * 64 + dd) * 1024 + t;  // transposed
            Vh[dst] = h_; Vl[dst] = l_;
          }
        } else {
          size_t o = (size_t)grow * N + col;
          out_f[o] = v + res[o];
        }
      }
}

// ---------------------------------------------------------------------------
// flash attention, fp16x3. grid: (T/64, B*H). block: 256 = 4 waves x 16 q-rows.
// Q/K layout [bh][t][d] (scaled 2^11 split); V layout [bh][d][t].
// ---------------------------------------------------------------------------
__global__ __launch_bounds__(256) void attn_f16x3(
    const _Float16* __restrict__ Qh, const _Float16* __restrict__ Ql,
    const _Float16* __restrict__ Kh, const _Float16* __restrict__ Kl,
    const _Float16* __restrict__ Vth, const _Float16* __restrict__ Vtl,
    _Float16* __restrict__ Ch, _Float16* __restrict__ Cl) {
  __shared__ _Float16 KsH[64][72], KsL[64][72], VsH[64][72], VsL[64][72];
  __shared__ _Float16 PsH[4][16][72], PsL[4][16][72];
  const int tid = threadIdx.x;
  const int lane = tid & 63, wave = tid >> 6;
  const int qr = lane & 15, lq = lane >> 4;
  const int bh = blockIdx.y;
  const size_t bo = (size_t)bh * 65536;
  const _Float16* Qhp = Qh + bo; const _Float16* Qlp = Ql + bo;
  const _Float16* Khp = Kh + bo; const _Float16* Klp = Kl + bo;
  const _Float16* Vhp = Vth + bo; const _Float16* Vlp = Vtl + bo;
  const int q0 = blockIdx.x * 64 + wave * 16;

  f16x8 qhf[2], qlf[2];
#pragma unroll
  for (int kc = 0; kc < 2; ++kc) {
    size_t qo = (size_t)(q0 + qr) * 64 + kc*32 + lq*8;
    qhf[kc] = *(const f16x8*)(Qhp + qo);
    qlf[kc] = *(const f16x8*)(Qlp + qo);
  }
  f32x4 o[4]; float m[4], l[4];
#pragma unroll
  for (int i = 0; i < 4; ++i) { o[i] = fzero4(); m[i] = -3.0e38f; l[i] = 0.f; }

  const int r0 = tid >> 3;        // 0..31
  const int k8 = (tid & 7) * 8;
  for (int kb = 0; kb < 16; ++kb) {
    __syncthreads();
#pragma unroll
    for (int j = 0; j < 2; ++j) {
      int rr = r0 + 32*j;
      *(uint4*)&KsH[rr][k8] = *(const uint4*)(Khp + (size_t)(kb*64 + rr)*64 + k8);
      *(uint4*)&KsL[rr][k8] = *(const uint4*)(Klp + (size_t)(kb*64 + rr)*64 + k8);
      *(uint4*)&VsH[rr][k8] = *(const uint4*)(Vhp + (size_t)rr*1024 + kb*64 + k8);
      *(uint4*)&VsL[rr][k8] = *(const uint4*)(Vlp + (size_t)rr*1024 + kb*64 + k8);
    }
    __syncthreads();
    f32x4 s[4];
#pragma unroll
    for (int nt = 0; nt < 4; ++nt) {
      f32x4 z = fzero4();
#pragma unroll
      for (int kc = 0; kc < 2; ++kc) {
        f16x8 kh_ = *(const f16x8*)&KsH[nt*16 + qr][kc*32 + lq*8];
        f16x8 kl_ = *(const f16x8*)&KsL[nt*16 + qr][kc*32 + lq*8];
        z = __builtin_amdgcn_mfma_f32_16x16x32_f16(qhf[kc], kh_, z, 0, 0, 0);
        z = __builtin_amdgcn_mfma_f32_16x16x32_f16(qhf[kc], kl_, z, 0, 0, 0);
        z = __builtin_amdgcn_mfma_f32_16x16x32_f16(qlf[kc], kh_, z, 0, 0, 0);
      }
      s[nt] = z;
    }
    const float sscale = 2.9802322387695312e-08f;  // 2^-22 * 0.125
#pragma unroll
    for (int r = 0; r < 4; ++r) {
#pragma unroll
      for (int nt = 0; nt < 4; ++nt) s[nt][r] *= sscale;
      float mx = fmaxf(fmaxf(s[0][r], s[1][r]), fmaxf(s[2][r], s[3][r]));
      mx = fmaxf(mx, __shfl_xor(mx, 1, 16));
      mx = fmaxf(mx, __shfl_xor(mx, 2, 16));
      mx = fmaxf(mx, __shfl_xor(mx, 4, 16));
      mx = fmaxf(mx, __shfl_xor(mx, 8, 16));
      float mn = fmaxf(m[r], mx);
      float al = __expf(m[r] - mn);
      m[r] = mn;
      float rs = 0.f;
#pragma unroll
      for (int nt = 0; nt < 4; ++nt) {
        float p = __expf(s[nt][r] - mn);
        s[nt][r] = p;
        rs += p;
      }
      rs += __shfl_xor(rs, 1, 16);
      rs += __shfl_xor(rs, 2, 16);
      rs += __shfl_xor(rs, 4, 16);
      rs += __shfl_xor(rs, 8, 16);
      l[r] = l[r] * al + rs;
#pragma unroll
      for (int dt = 0; dt < 4; ++dt) o[dt][r] *= al;
    }
    // P (scaled 2^11, split) -> per-wave LDS
#pragma unroll
    for (int nt = 0; nt < 4; ++nt)
#pragma unroll
      for (int r = 0; r < 4; ++r) {
        _Float16 ph, pl;
        splitf16(s[nt][r] * 2048.0f, &ph, &pl);
        PsH[wave][lq*4 + r][nt*16 + qr] = ph;
        PsL[wave][lq*4 + r][nt*16 + qr] = pl;
      }
    __syncthreads();
#pragma unroll
    for (int kc = 0; kc < 2; ++kc) {
      f16x8 pah = *(const f16x8*)&PsH[wave][qr][kc*32 + lq*8];
      f16x8 pal = *(const f16x8*)&PsL[wave][qr][kc*32 + lq*8];
#pragma unroll
      for (int dt = 0; dt < 4; ++dt) {
        f16x8 vh_ = *(const f16x8*)&VsH[dt*16 + qr][kc*32 + lq*8];
        f16x8 vl_ = *(const f16x8*)&VsL[dt*16 + qr][kc*32 + lq*8];
        o[dt] = __builtin_amdgcn_mfma_f32_16x16x32_f16(pah, vh_, o[dt], 0, 0, 0);
        o[dt] = __builtin_amdgcn_mfma_f32_16x16x32_f16(pah, vl_, o[dt], 0, 0, 0);
        o[dt] = __builtin_amdgcn_mfma_f32_16x16x32_f16(pal, vh_, o[dt], 0, 0, 0);
      }
    }
  }
  const int b = bh >> 4, hh = bh & 15;
  const float inv22 = 1.0f / 4194304.0f;  // 2^-22
#pragma unroll
  for (int dt = 0; dt < 4; ++dt)
#pragma unroll
    for (int r = 0; r < 4; ++r) {
      int tq = q0 + lq*4 + r;
      float v = o[dt][r] * inv22 / l[r];
      size_t idx = ((size_t)tq * 8 + b) * 1024 + hh*64 + dt*16 + qr;
      _Float16 h_, l_;
      splitf16(v * 2048.0f, &h_, &l_);
      Ch[idx] = h_; Cl[idx] = l_;
    }
}

// ---------------------------------------------------------------------------
// LayerNorm over C=1024. one block per row.
// ---------------------------------------------------------------------------
__global__ __launch_bounds__(256) void ln_kernel(
    const float* __restrict__ in, const float* __restrict__ g,
    const float* __restrict__ b, float* __restrict__ outf,
    unsigned short* __restrict__ outbf, int write_bf) {
  int row = blockIdx.x, tid = threadIdx.x;
  const float* xr = in + (size_t)row * 1024;
  float4 v = *(const float4*)(xr + tid*4);
  float s  = v.x + v.y + v.z + v.w;
  float sq = v.x*v.x + v.y*v.y + v.z*v.z + v.w*v.w;
#pragma unroll
  for (int off = 1; off < 64; off <<= 1) {
    s  += __shfl_xor(s, off, 64);
    sq += __shfl_xor(sq, off, 64);
  }
  __shared__ float red[8];
  int wv = tid >> 6, ln = tid & 63;
  if (ln == 0) { red[wv] = s; red[4 + wv] = sq; }
  __syncthreads();
  s  = red[0] + red[1] + red[2] + red[3];
  sq = red[4] + red[5] + red[6] + red[7];
  float mu   = s * 0.0009765625f;
  float var  = sq * 0.0009765625f - mu * mu;
  float rstd = 1.0f / sqrtf(var + 1e-5f);
  float4 gv = *(const float4*)(g + tid*4);
  float4 bv = *(const float4*)(b + tid*4);
  float4 o;
  o.x = (v.x - mu) * rstd * gv.x + bv.x;
  o.y = (v.y - mu) * rstd * gv.y + bv.y;
  o.z = (v.z - mu) * rstd * gv.z + bv.z;
  o.w = (v.w - mu) * rstd * gv.w + bv.w;
  *(float4*)(outf + (size_t)row * 1024 + tid*4) = o;
  if (write_bf) {
    ushort4 ob;
    ob.x = f2bf(o.x); ob.y = f2bf(o.y); ob.z = f2bf(o.z); ob.w = f2bf(o.w);
    *(ushort4*)(outbf + (size_t)row * 1024 + tid*4) = ob;
  }
}

// ---------------------------------------------------------------------------
// router: fp32 logits, top-2, assign = max(top2 indices). one wave per token.
// ---------------------------------------------------------------------------
__global__ __launch_bounds__(256) void router_kernel(
    const float* __restrict__ h, const float* __restrict__ rw,
    const float* __restrict__ rb, int* __restrict__ assign) {
  int tok = blockIdx.x * 4 + (threadIdx.x >> 6);
  int lane = threadIdx.x & 63;
  const float* hr = h + (size_t)tok * 1024;
  float acc[8];
#pragma unroll
  for (int e = 0; e < 8; ++e) acc[e] = 0.f;
#pragma unroll
  for (int j = 0; j < 4; ++j) {
    float4 hv = *(const float4*)(hr + lane*4 + j*256);
#pragma unroll
    for (int e = 0; e < 8; ++e) {
      float4 wv = *(const float4*)(rw + e*1024 + lane*4 + j*256);
      acc[e] += hv.x*wv.x + hv.y*wv.y + hv.z*wv.z + hv.w*wv.w;
    }
  }
#pragma unroll
  for (int e = 0; e < 8; ++e) {
#pragma unroll
    for (int off = 1; off < 64; off <<= 1) acc[e] += __shfl_xor(acc[e], off, 64);
    acc[e] += rb[e];
  }
  if (lane == 0) {
    int i1 = 0; float v1 = acc[0];
#pragma unroll
    for (int e = 1; e < 8; ++e) if (acc[e] > v1) { v1 = acc[e]; i1 = e; }
    int i2 = -1; float v2 = -3.0e38f;
#pragma unroll
    for (int e = 0; e < 8; ++e) if (e != i1 && acc[e] > v2) { v2 = acc[e]; i2 = e; }
    assign[tok] = (i1 > i2) ? i1 : i2;
  }
}

// ---------------------------------------------------------------------------
// expert bucketing
// ---------------------------------------------------------------------------
__global__ void zero_kernel(int* __restrict__ counts) {
  if (threadIdx.x < 16) counts[threadIdx.x] = 0;
}
__global__ void count_kernel(const int* __restrict__ assign, int* __restrict__ counts) {
  int i = blockIdx.x * 256 + threadIdx.x;
  if (i < 8192) atomicAdd(&counts[assign[i]], 1);
}
__global__ void scatter_kernel(const int* __restrict__ assign, int* __restrict__ counts,
                               int* __restrict__ list) {
  int i = blockIdx.x * 256 + threadIdx.x;
  if (i >= 8192) return;
  int a = assign[i];
  int base = 0;
  for (int e = 0; e < a; ++e) base += counts[e];
  int pos = atomicAdd(&counts[8 + a], 1);
  list[base + pos] = i;
}

// ---------------------------------------------------------------------------
// grouped MoE GEMM, bf16. grid (8, 64, E). 128x128 tile, BK=64.
// EPI 2: A = h_bf gathered via list; out = gelu(acc+b1) -> he (compact rows)
// EPI 3: A = he compact; out = acc + b2 + h[n] -> tmp[n] (scatter)
// ---------------------------------------------------------------------------
template<int EPI>
__global__ __launch_bounds__(256) void gemm_moe(
    const unsigned short* __restrict__ A, const unsigned short* __restrict__ Bw,
    const float* __restrict__ bias, const float* __restrict__ res,
    float* __restrict__ out_f, unsigned short* __restrict__ out_bf,
    const int* __restrict__ list, const int* __restrict__ counts) {
  const int e = blockIdx.z;
  const int cnt = counts[e];
  if ((int)blockIdx.y * 128 >= cnt) return;
  int base = 0;
  for (int i = 0; i < 8; ++i) if (i < e) base += counts[i];
  const unsigned short* Bp = Bw + (size_t)e * 1048576;
  const float* biasp = bias + e * 1024;

  __shared__ unsigned short As[128][72], Bs[128][72];
  const int tid = threadIdx.x;
  const int lane = tid & 63, wave = tid >> 6;
  const int wm = wave >> 1, wn = wave & 1;
  const int qr = lane & 15, lq = lane >> 4;
  const int rowBase = blockIdx.y * 128, colBase = blockIdx.x * 128;

  const int r0 = tid >> 3;        // 0..31
  const int k8 = (tid & 7) * 8;
  const unsigned short *pA[4], *pB[4];
#pragma unroll
  for (int j = 0; j < 4; ++j) {
    int rl = r0 + 32*j;
    int grow = rowBase + rl;
    int gi = (grow < cnt) ? grow : (cnt - 1);
    int arow = (EPI == 2) ? list[base + gi] : (base + gi);
    pA[j] = A + (size_t)arow * 1024 + k8;
    pB[j] = Bp + (size_t)(colBase + rl) * 1024 + k8;
  }
  f32x4 acc[4][4];
#pragma unroll
  for (int m2 = 0; m2 < 4; ++m2)
#pragma unroll
    for (int n2 = 0; n2 < 4; ++n2) acc[m2][n2] = fzero4();

  uint4 sA[4], sB[4];
#pragma unroll
  for (int j = 0; j < 4; ++j) { sA[j] = *(const uint4*)pA[j]; sB[j] = *(const uint4*)pB[j]; }
  for (int kt = 0; kt < 16; ++kt) {
    __syncthreads();
#pragma unroll
    for (int j = 0; j < 4; ++j) {
      int rr = r0 + 32*j;
      *(uint4*)&As[rr][k8] = sA[j];
      *(uint4*)&Bs[rr][k8] = sB[j];
    }
    __syncthreads();
    if (kt + 1 < 16) {
      int off = (kt + 1) * 64;
#pragma unroll
      for (int j = 0; j < 4; ++j) {
        sA[j] = *(const uint4*)(pA[j] + off);
        sB[j] = *(const uint4*)(pB[j] + off);
      }
    }
    bf16x8 af[2][4], bf[2][4];
#pragma unroll
    for (int mt = 0; mt < 4; ++mt) {
      af[0][mt] = *(const bf16x8*)&As[wm*64 + mt*16 + qr][lq*8];
      af[1][mt] = *(const bf16x8*)&As[wm*64 + mt*16 + qr][32 + lq*8];
    }
#pragma unroll
    for (int nt = 0; nt < 4; ++nt) {
      bf[0][nt] = *(const bf16x8*)&Bs[wn*64 + nt*16 + qr][lq*8];
      bf[1][nt] = *(const bf16x8*)&Bs[wn*64 + nt*16 + qr][32 + lq*8];
    }
#pragma unroll
    for (int kc = 0; kc < 2; ++kc)
#pragma unroll
      for (int mt = 0; mt < 4; ++mt)
#pragma unroll
        for (int nt = 0; nt < 4; ++nt)
          acc[mt][nt] = __builtin_amdgcn_mfma_f32_16x16x32_bf16(
              af[kc][mt], bf[kc][nt], acc[mt][nt], 0, 0, 0);
  }
#pragma unroll
  for (int mt = 0; mt < 4; ++mt)
#pragma unroll
    for (int nt = 0; nt < 4; ++nt)
#pragma unroll
      for (int r = 0; r < 4; ++r) {
        int grow = rowBase + wm*64 + mt*16 + lq*4 + r;
        int col  = colBase + wn*64 + nt*16 + qr;
        if (grow < cnt) {
          float v = acc[mt][nt][r] + biasp[col];
          if (EPI == 2) {
            float ge = 0.5f * v * (1.0f + erff(v * 0.70710678118654752f));
            out_bf[(size_t)(base + grow) * 1024 + col] = f2bf(ge);
          } else {
            int n = list[base + grow];
            size_t o2 = (size_t)n * 1024 + col;
            out_f[o2] = v + res[o2];
          }
        }
      }
}

// ---------------------------------------------------------------------------
extern "C" void kernel_launch(void* const* d_in, const int* in_sizes, int n_in,
                              void* d_out, int out_size, void* d_ws, size_t ws_size,
                              hipStream_t stream) {
  const float* x   = (const float*)d_in[0];
  const float* ipw = (const float*)d_in[1];
  const float* ipb = (const float*)d_in[2];
  const float* ow  = (const float*)d_in[3];
  const float* ob  = (const float*)d_in[4];
  const float* g1  = (const float*)d_in[5];
  const float* b1n = (const float*)d_in[6];
  const float* rw  = (const float*)d_in[7];
  const float* rb  = (const float*)d_in[8];
  const float* w1  = (const float*)d_in[9];
  const float* b1e = (const float*)d_in[10];
  const float* w2  = (const float*)d_in[11];
  const float* b2e = (const float*)d_in[12];
  const float* g2  = (const float*)d_in[13];
  const float* b2n = (const float*)d_in[14];

  char* ws = (char*)d_ws;
  const size_t MB = 1048576;
  _Float16* Xh  = (_Float16*)(ws + 0*MB);
  _Float16* Xl  = (_Float16*)(ws + 16*MB);
  _Float16* Wih = (_Float16*)(ws + 32*MB);
  _Float16* Wil = (_Float16*)(ws + 38*MB);
  _Float16* Woh = (_Float16*)(ws + 44*MB);
  _Float16* Wol = (_Float16*)(ws + 46*MB);
  unsigned short* w1b = (unsigned short*)(ws + 48*MB);
  unsigned short* w2b = (unsigned short*)(ws + 64*MB);
  _Float16* Qh  = (_Float16*)(ws + 80*MB);
  _Float16* Ql  = (_Float16*)(ws + 96*MB);
  _Float16* Kh  = (_Float16*)(ws + 112*MB);
  _Float16* Kl  = (_Float16*)(ws + 128*MB);
  _Float16* Vth = (_Float16*)(ws + 144*MB);
  _Float16* Vtl = (_Float16*)(ws + 160*MB);
  // overlays of dead regions:
  _Float16* Ch  = Xh;                                     // ctx hi (X dead)
  _Float16* Cl  = Xl;                                     // ctx lo
  float* tmp    = (float*)(ws + 80*MB);                   // over Q (dead post-attn)
  float* hbuf   = (float*)(ws + 112*MB);                  // over K
  unsigned short* hbf = (unsigned short*)(ws + 144*MB);   // over Vth
  unsigned short* he  = (unsigned short*)(ws + 160*MB);   // over Vtl
  int* assign = (int*)(ws + 176*MB);
  int* list   = (int*)(ws + 176*MB + 32768);
  int* counts = (int*)(ws + 176*MB + 65536);

  // 1) precision-split / cast weights & activations
  split_kernel<<<8192, 256, 0, stream>>>(x,   Xh,  Xl,  2048.0f, 2097152);
  split_kernel<<<3072, 256, 0, stream>>>(ipw, Wih, Wil, 1024.0f, 786432);
  split_kernel<<<1024, 256, 0, stream>>>(ow,  Woh, Wol, 1024.0f, 262144);
  castbf_kernel<<<8192, 256, 0, stream>>>(w1, w1b, 2097152);
  castbf_kernel<<<8192, 256, 0, stream>>>(w2, w2b, 2097152);

  // 2) QKV projection (fp16x3), epilogue scatters per-head Q/K/V(transposed)
  gemm_f16x3<0><<<dim3(24, 64), 256, 0, stream>>>(
      Xh, Xl, Wih, Wil, ipb, 3072, 1024, nullptr, nullptr,
      Qh, Ql, Kh, Kl, Vth, Vtl);

  // 3) flash attention
  attn_f16x3<<<dim3(16, 128), 256, 0, stream>>>(Qh, Ql, Kh, Kl, Vth, Vtl, Ch, Cl);

  // 4) out-proj + residual(x) -> tmp
  gemm_f16x3<1><<<dim3(8, 64), 256, 0, stream>>>(
      Ch, Cl, Woh, Wol, ob, 1024, 1024, tmp, x,
      nullptr, nullptr, nullptr, nullptr, nullptr, nullptr);

  // 5) LN1 -> h (fp32) + h_bf
  ln_kernel<<<8192, 256, 0, stream>>>(tmp, g1, b1n, hbuf, hbf, 1);

  // 6) router -> assign; bucket tokens per expert
  router_kernel<<<2048, 256, 0, stream>>>(hbuf, rw, rb, assign);
  zero_kernel<<<1, 64, 0, stream>>>(counts);
  count_kernel<<<32, 256, 0, stream>>>(assign, counts);
  scatter_kernel<<<32, 256, 0, stream>>>(assign, counts, list);

  // 7) MoE FFN (bf16): he = gelu(h@w1^T+b1) ; tmp = h + (he@w2^T+b2)
  gemm_moe<2><<<dim3(8, 64, 8), 256, 0, stream>>>(
      hbf, w1b, b1e, nullptr, nullptr, he, list, counts);
  gemm_moe<3><<<dim3(8, 64, 8), 256, 0, stream>>>(
      he, w2b, b2e, hbuf, tmp, nullptr, list, counts);

  // 8) LN2 -> d_out
  ln_kernel<<<8192, 256, 0, stream>>>(tmp, g2, b2n, (float*)d_out, nullptr, 0);
}

// Round 2
// 1163.131 us; speedup vs baseline: 1.3605x; 1.3605x over previous
//
#include <hip/hip_runtime.h>
#include <math.h>

// ---------------------------------------------------------------------------
// StandardMoELayer on MI355X.
// Precision strategy: everything upstream of the router (QKV, attention,
// out-proj, LN1) must be fp32-accurate or top-2 routing flips vs the numpy
// reference. fp16x3 split-MFMA upstream; bf16 MFMA for post-router MoE FFN.
// R2: gemm_f16x3 rebuilt — global_load_lds staging (pre-swizzled source),
// XCD-chunked grid for B-panel L2 residency, LDS-restaged coalesced epilogue.
// ---------------------------------------------------------------------------

typedef __attribute__((ext_vector_type(4))) float f32x4;
typedef __attribute__((ext_vector_type(8))) _Float16 f16x8;
typedef __attribute__((ext_vector_type(4))) _Float16 f16x4;
typedef __attribute__((ext_vector_type(8))) short bf16x8;

#define DEVI static __device__ __forceinline__

DEVI unsigned short f2bf(float f) {
  unsigned int u = __builtin_bit_cast(unsigned int, f);
  return (unsigned short)((u + 0x7fffu + ((u >> 16) & 1u)) >> 16);
}

DEVI f32x4 fzero4() { f32x4 z; z[0]=0.f; z[1]=0.f; z[2]=0.f; z[3]=0.f; return z; }

DEVI void splitf16(float v, _Float16* hi, _Float16* lo) {
  _Float16 h = (_Float16)v;
  *hi = h;
  *lo = (_Float16)(v - (float)h);
}

DEVI void gload16(const void* g, void* l) {
  __builtin_amdgcn_global_load_lds(
      (__attribute__((address_space(1))) void*)(g),
      (__attribute__((address_space(3))) void*)(l), 16, 0, 0);
}

// ---------------------------------------------------------------------------
// elementwise prep kernels
// ---------------------------------------------------------------------------
__global__ void split_kernel(const float* __restrict__ in,
                             _Float16* __restrict__ oh, _Float16* __restrict__ ol,
                             float scale, int n4) {
  int i = blockIdx.x * 256 + threadIdx.x;
  if (i >= n4) return;
  float4 v = ((const float4*)in)[i];
  f16x4 hv, lv; _Float16 hh, ll;
  splitf16(v.x * scale, &hh, &ll); hv[0]=hh; lv[0]=ll;
  splitf16(v.y * scale, &hh, &ll); hv[1]=hh; lv[1]=ll;
  splitf16(v.z * scale, &hh, &ll); hv[2]=hh; lv[2]=ll;
  splitf16(v.w * scale, &hh, &ll); hv[3]=hh; lv[3]=ll;
  ((f16x4*)oh)[i] = hv;
  ((f16x4*)ol)[i] = lv;
}

__global__ void castbf_kernel(const float* __restrict__ in,
                              unsigned short* __restrict__ o, int n4) {
  int i = blockIdx.x * 256 + threadIdx.x;
  if (i >= n4) return;
  float4 v = ((const float4*)in)[i];
  ushort4 r;
  r.x = f2bf(v.x); r.y = f2bf(v.y); r.z = f2bf(v.z); r.w = f2bf(v.w);
  ((ushort4*)o)[i] = r;
}

// ---------------------------------------------------------------------------
// fp16x3 GEMM: C[M=8192,N] = A[M,K] * W[N,K]^T  (A scaled 2^11, W scaled 2^10)
// 128x128 tile, BK=32, 4 waves. global_load_lds staging, swizzled granules.
// grid: 1D, XCD-chunked: each XCD owns nColB/8 col-panels, sweeps rows with
// col fastest so B panels stay L2-resident.
// EPI 0: +bias, LDS-restage, coalesced split-store Q/K ([bh][t][d]) and
//        V transposed ([bh][d][t]).
// EPI 1: +bias +res -> fp32 out (direct coalesced stores)
// ---------------------------------------------------------------------------
template<int EPI>
__global__ __launch_bounds__(256) void gemm_f16x3(
    const _Float16* __restrict__ Ah, const _Float16* __restrict__ Al,
    const _Float16* __restrict__ Bh, const _Float16* __restrict__ Bl,
    const float* __restrict__ bias, int N, int K,
    float* __restrict__ out_f, const float* __restrict__ res,
    _Float16* __restrict__ Qh, _Float16* __restrict__ Ql,
    _Float16* __restrict__ Kh, _Float16* __restrict__ Kl,
    _Float16* __restrict__ Vh, _Float16* __restrict__ Vl) {
  __shared__ __align__(16) char smem[32768];  // 4 arrays x [128 rows][64 B]
  const int tid = threadIdx.x;
  const int lane = tid & 63, wave = tid >> 6;
  const int wm = wave >> 1, wn = wave & 1;
  const int qr = lane & 15, lq = lane >> 4;

  // XCD-chunked block remap (nwg % 8 == 0 always here)
  const int cpx = gridDim.x >> 3;
  const int xcd = blockIdx.x & 7, idx = blockIdx.x >> 3;
  const int colsPerX = (N >> 7) >> 3;
  const int rowb = idx / colsPerX;
  const int colb = xcd * colsPerX + (idx - rowb * colsPerX);
  (void)cpx;
  const int rowBase = rowb * 128, colBase = colb * 128;

  // staging source pointers: granule-swizzled per-lane global addresses,
  // linear LDS dest (global_load_lds: wave-uniform base + lane*16).
  const char* gsrc[8];
  unsigned ldso[8];
  {
    const int srow = (wave << 4) + (lane >> 2);  // 0..63 within 64-row half
    const int sg = lane & 3;
#pragma unroll
    for (int i = 0; i < 8; ++i) {
      int a = i >> 1, j = i & 1;
      int row = j * 64 + srow;
      int gs = sg ^ ((row >> 1) & 3);
      const _Float16* basep = (a == 0) ? Ah : (a == 1) ? Al : (a == 2) ? Bh : Bl;
      int R0 = (a < 2) ? rowBase : colBase;
      gsrc[i] = (const char*)(basep + (size_t)(R0 + row) * K) + gs * 16;
      ldso[i] = a * 8192 + j * 4096 + wave * 1024;  // wave-uniform
    }
  }

  f32x4 acc[4][4];
#pragma unroll
  for (int m = 0; m < 4; ++m)
#pragma unroll
    for (int n = 0; n < 4; ++n) acc[m][n] = fzero4();

  const int gfr = (qr >> 1) & 3;  // frag granule swizzle term
  const int NT = K >> 5;
  for (int kt = 0; kt < NT; ++kt) {
    __syncthreads();
#pragma unroll
    for (int i = 0; i < 8; ++i) gload16(gsrc[i], smem + ldso[i]);
    __syncthreads();
#pragma unroll
    for (int i = 0; i < 8; ++i) gsrc[i] += 64;

    f16x8 ahf[4], alf[4], bhf[4], blf[4];
#pragma unroll
    for (int mt = 0; mt < 4; ++mt) {
      int off = (wm * 64 + mt * 16 + qr) * 64 + ((lq ^ gfr) * 16);
      ahf[mt] = *(const f16x8*)(smem + off);
      alf[mt] = *(const f16x8*)(smem + 8192 + off);
    }
#pragma unroll
    for (int nt = 0; nt < 4; ++nt) {
      int off = (wn * 64 + nt * 16 + qr) * 64 + ((lq ^ gfr) * 16);
      bhf[nt] = *(const f16x8*)(smem + 16384 + off);
      blf[nt] = *(const f16x8*)(smem + 24576 + off);
    }
#pragma unroll
    for (int mt = 0; mt < 4; ++mt)
#pragma unroll
      for (int nt = 0; nt < 4; ++nt) {
        f32x4 c = acc[mt][nt];
        c = __builtin_amdgcn_mfma_f32_16x16x32_f16(ahf[mt], bhf[nt], c, 0, 0, 0);
        c = __builtin_amdgcn_mfma_f32_16x16x32_f16(ahf[mt], blf[nt], c, 0, 0, 0);
        c = __builtin_amdgcn_mfma_f32_16x16x32_f16(alf[mt], bhf[nt], c, 0, 0, 0);
        acc[mt][nt] = c;
      }
  }

  const float inv21 = 1.0f / 2097152.0f;  // 2^-21
  float biasv[4];
#pragma unroll
  for (int nt = 0; nt < 4; ++nt) biasv[nt] = bias[colBase + wn * 64 + nt * 16 + qr];

  if (EPI == 0) {
    __syncthreads();  // staging LDS reusable now
    const int sect = colBase >> 10;                // 0=Q 1=K 2=V (block-uniform)
    const int hhBase = (colBase & 1023) >> 6;
    const int t0 = rowBase >> 3;
    _Float16* L = (_Float16*)smem;                 // 16384 fp16 = 32 KB
    _Float16* dstH = (sect == 0) ? Qh : (sect == 1) ? Kh : Vh;
    _Float16* dstL = (sect == 0) ? Ql : (sect == 1) ? Kl : Vl;
#pragma unroll
    for (int pass = 0; pass < 2; ++pass) {
      if (pass) __syncthreads();
      // scatter acc into LDS in output-linear layout
#pragma unroll
      for (int mt = 0; mt < 4; ++mt)
#pragma unroll
        for (int nt = 0; nt < 4; ++nt)
#pragma unroll
          for (int r = 0; r < 4; ++r) {
            int rl = wm * 64 + mt * 16 + lq * 4 + r;
            int cl = wn * 64 + nt * 16 + qr;
            float v = acc[mt][nt][r] * inv21 + biasv[nt];
            _Float16 h_, l_;
            splitf16(v * 2048.0f, &h_, &l_);
            int off;
            if (sect < 2)
              off = ((rl & 7) * 2 + (cl >> 6)) * 1024 + (rl >> 3) * 64 + (cl & 63);
            else
              off = (cl >> 6) * 8192 + (cl & 63) * 128 + (rl & 7) * 16 + (rl >> 3);
            L[off] = pass ? l_ : h_;
          }
      __syncthreads();
      _Float16* dst = pass ? dstL : dstH;
      if (sect < 2) {
#pragma unroll
        for (int j = 0; j < 8; ++j) {
          int c = j * 256 + tid;                   // 16B chunk id, 0..2047
          int b = c >> 8, hh = (c >> 7) & 1;
          int tl = (c >> 3) & 15, dd = (c & 7) * 8;
          size_t gd = ((size_t)(b * 16 + hhBase + hh) << 16) +
                      (size_t)(t0 + tl) * 64 + dd;
          *(uint4*)(dst + gd) = *(const uint4*)(L + (size_t)c * 8);
        }
      } else {
#pragma unroll
        for (int j = 0; j < 4; ++j) {
          int c = j * 256 + tid;                   // 32B chunk id, 0..1023
          int hh = c >> 9, dd = (c >> 3) & 63, b = c & 7;
          size_t gd = ((size_t)(b * 16 + hhBase + hh) << 16) +
                      (size_t)dd * 1024 + t0;
          *(uint4*)(dst + gd)     = *(const uint4*)(L + (size_t)c * 16);
          *(uint4*)(dst + gd + 8) = *(const uint4*)(L + (size_t)c * 16 + 8);
        }
      }
    }
  } else {
#pragma unroll
    for (int mt = 0; mt < 4; ++mt)
#pragma unroll
      for (int nt = 0; nt < 4; ++nt)
#pragma unroll
        for (int r = 0; r < 4; ++r) {
          int grow = rowBase + wm * 64 + mt * 16 + lq * 4 + r;
          int col = colBase + wn * 64 + nt * 16 + qr;
          size_t o = (size_t)grow * N + col;
          out_f[o] = acc[mt][nt][r] * inv21 + biasv[nt] + res[o];
        }
  }
}

// ---------------------------------------------------------------------------
// flash attention, fp16x3. grid: (T/64, B*H). block: 256 = 4 waves x 16 q-rows.
// Q/K layout [bh][t][d] (scaled 2^11 split); V layout [bh][d][t].
// ---------------------------------------------------------------------------
__global__ __launch_bounds__(256) void attn_f16x3(
    const _Float16* __restrict__ Qh, const _Float16* __restrict__ Ql,
    const _Float16* __restrict__ Kh, const _Float16* __restrict__ Kl,
    const _Float16* __restrict__ Vth, const _Float16* __restrict__ Vtl,
    _Float16* __restrict__ Ch, _Float16* __restrict__ Cl) {
  __shared__ _Float16 KsH[64][72], KsL[64][72], VsH[64][72], VsL[64][72];
  __shared__ _Float16 PsH[4][16][72], PsL[4][16][72];
  const int tid = threadIdx.x;
  const int lane = tid & 63, wave = tid >> 6;
  const int qr = lane & 15, lq = lane >> 4;
  const int bh = blockIdx.y;
  const size_t bo = (size_t)bh * 65536;
  const _Float16* Qhp = Qh + bo; const _Float16* Qlp = Ql + bo;
  const _Float16* Khp = Kh + bo; const _Float16* Klp = Kl + bo;
  const _Float16* Vhp = Vth + bo; const _Float16* Vlp = Vtl + bo;
  const int q0 = blockIdx.x * 64 + wave * 16;

  f16x8 qhf[2], qlf[2];
#pragma unroll
  for (int kc = 0; kc < 2; ++kc) {
    size_t qo = (size_t)(q0 + qr) * 64 + kc*32 + lq*8;
    qhf[kc] = *(const f16x8*)(Qhp + qo);
    qlf[kc] = *(const f16x8*)(Qlp + qo);
  }
  f32x4 o[4]; float m[4], l[4];
#pragma unroll
  for (int i = 0; i < 4; ++i) { o[i] = fzero4(); m[i] = -3.0e38f; l[i] = 0.f; }

  const int r0 = tid >> 3;        // 0..31
  const int k8 = (tid & 7) * 8;
  for (int kb = 0; kb < 16; ++kb) {
    __syncthreads();
#pragma unroll
    for (int j = 0; j < 2; ++j) {
      int rr = r0 + 32*j;
      *(uint4*)&KsH[rr][k8] = *(const uint4*)(Khp + (size_t)(kb*64 + rr)*64 + k8);
      *(uint4*)&KsL[rr][k8] = *(const uint4*)(Klp + (size_t)(kb*64 + rr)*64 + k8);
      *(uint4*)&VsH[rr][k8] = *(const uint4*)(Vhp + (size_t)rr*1024 + kb*64 + k8);
      *(uint4*)&VsL[rr][k8] = *(const uint4*)(Vlp + (size_t)rr*1024 + kb*64 + k8);
    }
    __syncthreads();
    f32x4 s[4];
#pragma unroll
    for (int nt = 0; nt < 4; ++nt) {
      f32x4 z = fzero4();
#pragma unroll
      for (int kc = 0; kc < 2; ++kc) {
        f16x8 kh_ = *(const f16x8*)&KsH[nt*16 + qr][kc*32 + lq*8];
        f16x8 kl_ = *(const f16x8*)&KsL[nt*16 + qr][kc*32 + lq*8];
        z = __builtin_amdgcn_mfma_f32_16x16x32_f16(qhf[kc], kh_, z, 0, 0, 0);
        z = __builtin_amdgcn_mfma_f32_16x16x32_f16(qhf[kc], kl_, z, 0, 0, 0);
        z = __builtin_amdgcn_mfma_f32_16x16x32_f16(qlf[kc], kh_, z, 0, 0, 0);
      }
      s[nt] = z;
    }
    const float sscale = 2.9802322387695312e-08f;  // 2^-22 * 0.125
#pragma unroll
    for (int r = 0; r < 4; ++r) {
#pragma unroll
      for (int nt = 0; nt < 4; ++nt) s[nt][r] *= sscale;
      float mx = fmaxf(fmaxf(s[0][r], s[1][r]), fmaxf(s[2][r], s[3][r]));
      mx = fmaxf(mx, __shfl_xor(mx, 1, 16));
      mx = fmaxf(mx, __shfl_xor(mx, 2, 16));
      mx = fmaxf(mx, __shfl_xor(mx, 4, 16));
      mx = fmaxf(mx, __shfl_xor(mx, 8, 16));
      float mn = fmaxf(m[r], mx);
      float al = __expf(m[r] - mn);
      m[r] = mn;
      float rs = 0.f;
#pragma unroll
      for (int nt = 0; nt < 4; ++nt) {
        float p = __expf(s[nt][r] - mn);
        s[nt][r] = p;
        rs += p;
      }
      rs += __shfl_xor(rs, 1, 16);
      rs += __shfl_xor(rs, 2, 16);
      rs += __shfl_xor(rs, 4, 16);
      rs += __shfl_xor(rs, 8, 16);
      l[r] = l[r] * al + rs;
#pragma unroll
      for (int dt = 0; dt < 4; ++dt) o[dt][r] *= al;
    }
#pragma unroll
    for (int nt = 0; nt < 4; ++nt)
#pragma unroll
      for (int r = 0; r < 4; ++r) {
        _Float16 ph, pl;
        splitf16(s[nt][r] * 2048.0f, &ph, &pl);
        PsH[wave][lq*4 + r][nt*16 + qr] = ph;
        PsL[wave][lq*4 + r][nt*16 + qr] = pl;
      }
    __syncthreads();
#pragma unroll
    for (int kc = 0; kc < 2; ++kc) {
      f16x8 pah = *(const f16x8*)&PsH[wave][qr][kc*32 + lq*8];
      f16x8 pal = *(const f16x8*)&PsL[wave][qr][kc*32 + lq*8];
#pragma unroll
      for (int dt = 0; dt < 4; ++dt) {
        f16x8 vh_ = *(const f16x8*)&VsH[dt*16 + qr][kc*32 + lq*8];
        f16x8 vl_ = *(const f16x8*)&VsL[dt*16 + qr][kc*32 + lq*8];
        o[dt] = __builtin_amdgcn_mfma_f32_16x16x32_f16(pah, vh_, o[dt], 0, 0, 0);
        o[dt] = __builtin_amdgcn_mfma_f32_16x16x32_f16(pah, vl_, o[dt], 0, 0, 0);
        o[dt] = __builtin_amdgcn_mfma_f32_16x16x32_f16(pal, vh_, o[dt], 0, 0, 0);
      }
    }
  }
  const int b = bh >> 4, hh = bh & 15;
  const float inv22 = 1.0f / 4194304.0f;  // 2^-22
#pragma unroll
  for (int dt = 0; dt < 4; ++dt)
#pragma unroll
    for (int r = 0; r < 4; ++r) {
      int tq = q0 + lq*4 + r;
      float v = o[dt][r] * inv22 / l[r];
      size_t idx = ((size_t)tq * 8 + b) * 1024 + hh*64 + dt*16 + qr;
      _Float16 h_, l_;
      splitf16(v * 2048.0f, &h_, &l_);
      Ch[idx] = h_; Cl[idx] = l_;
    }
}

// ---------------------------------------------------------------------------
// LayerNorm over C=1024. one block per row.
// ---------------------------------------------------------------------------
__global__ __launch_bounds__(256) void ln_kernel(
    const float* __restrict__ in, const float* __restrict__ g,
    const float* __restrict__ b, float* __restrict__ outf,
    unsigned short* __restrict__ outbf, int write_bf) {
  int row = blockIdx.x, tid = threadIdx.x;
  const float* xr = in + (size_t)row * 1024;
  float4 v = *(const float4*)(xr + tid*4);
  float s  = v.x + v.y + v.z + v.w;
  float sq = v.x*v.x + v.y*v.y + v.z*v.z + v.w*v.w;
#pragma unroll
  for (int off = 1; off < 64; off <<= 1) {
    s  += __shfl_xor(s, off, 64);
    sq += __shfl_xor(sq, off, 64);
  }
  __shared__ float red[8];
  int wv = tid >> 6, ln = tid & 63;
  if (ln == 0) { red[wv] = s; red[4 + wv] = sq; }
  __syncthreads();
  s  = red[0] + red[1] + red[2] + red[3];
  sq = red[4] + red[5] + red[6] + red[7];
  float mu   = s * 0.0009765625f;
  float var  = sq * 0.0009765625f - mu * mu;
  float rstd = 1.0f / sqrtf(var + 1e-5f);
  float4 gv = *(const float4*)(g + tid*4);
  float4 bv = *(const float4*)(b + tid*4);
  float4 o;
  o.x = (v.x - mu) * rstd * gv.x + bv.x;
  o.y = (v.y - mu) * rstd * gv.y + bv.y;
  o.z = (v.z - mu) * rstd * gv.z + bv.z;
  o.w = (v.w - mu) * rstd * gv.w + bv.w;
  *(float4*)(outf + (size_t)row * 1024 + tid*4) = o;
  if (write_bf) {
    ushort4 ob;
    ob.x = f2bf(o.x); ob.y = f2bf(o.y); ob.z = f2bf(o.z); ob.w = f2bf(o.w);
    *(ushort4*)(outbf + (size_t)row * 1024 + tid*4) = ob;
  }
}

// ---------------------------------------------------------------------------
// router: fp32 logits, top-2, assign = max(top2 indices). one wave per token.
// ---------------------------------------------------------------------------
__global__ __launch_bounds__(256) void router_kernel(
    const float* __restrict__ h, const float* __restrict__ rw,
    const float* __restrict__ rb, int* __restrict__ assign) {
  int tok = blockIdx.x * 4 + (threadIdx.x >> 6);
  int lane = threadIdx.x & 63;
  const float* hr = h + (size_t)tok * 1024;
  float acc[8];
#pragma unroll
  for (int e = 0; e < 8; ++e) acc[e] = 0.f;
#pragma unroll
  for (int j = 0; j < 4; ++j) {
    float4 hv = *(const float4*)(hr + lane*4 + j*256);
#pragma unroll
    for (int e = 0; e < 8; ++e) {
      float4 wv = *(const float4*)(rw + e*1024 + lane*4 + j*256);
      acc[e] += hv.x*wv.x + hv.y*wv.y + hv.z*wv.z + hv.w*wv.w;
    }
  }
#pragma unroll
  for (int e = 0; e < 8; ++e) {
#pragma unroll
    for (int off = 1; off < 64; off <<= 1) acc[e] += __shfl_xor(acc[e], off, 64);
    acc[e] += rb[e];
  }
  if (lane == 0) {
    int i1 = 0; float v1 = acc[0];
#pragma unroll
    for (int e = 1; e < 8; ++e) if (acc[e] > v1) { v1 = acc[e]; i1 = e; }
    int i2 = -1; float v2 = -3.0e38f;
#pragma unroll
    for (int e = 0; e < 8; ++e) if (e != i1 && acc[e] > v2) { v2 = acc[e]; i2 = e; }
    assign[tok] = (i1 > i2) ? i1 : i2;
  }
}

// ---------------------------------------------------------------------------
// expert bucketing
// ---------------------------------------------------------------------------
__global__ void zero_kernel(int* __restrict__ counts) {
  if (threadIdx.x < 16) counts[threadIdx.x] = 0;
}
__global__ void count_kernel(const int* __restrict__ assign, int* __restrict__ counts) {
  int i = blockIdx.x * 256 + threadIdx.x;
  if (i < 8192) atomicAdd(&counts[assign[i]], 1);
}
__global__ void scatter_kernel(const int* __restrict__ assign, int* __restrict__ counts,
                               int* __restrict__ list) {
  int i = blockIdx.x * 256 + threadIdx.x;
  if (i >= 8192) return;
  int a = assign[i];
  int base = 0;
  for (int e = 0; e < a; ++e) base += counts[e];
  int pos = atomicAdd(&counts[8 + a], 1);
  list[base + pos] = i;
}

// ---------------------------------------------------------------------------
// grouped MoE GEMM, bf16. grid (8, 64, E). 128x128 tile, BK=64.
// ---------------------------------------------------------------------------
template<int EPI>
__global__ __launch_bounds__(256) void gemm_moe(
    const unsigned short* __restrict__ A, const unsigned short* __restrict__ Bw,
    const float* __restrict__ bias, const float* __restrict__ res,
    float* __restrict__ out_f, unsigned short* __restrict__ out_bf,
    const int* __restrict__ list, const int* __restrict__ counts) {
  const int e = blockIdx.z;
  const int cnt = counts[e];
  if ((int)blockIdx.y * 128 >= cnt) return;
  int base = 0;
  for (int i = 0; i < 8; ++i) if (i < e) base += counts[i];
  const unsigned short* Bp = Bw + (size_t)e * 1048576;
  const float* biasp = bias + e * 1024;

  __shared__ unsigned short As[128][72], Bs[128][72];
  const int tid = threadIdx.x;
  const int lane = tid & 63, wave = tid >> 6;
  const int wm = wave >> 1, wn = wave & 1;
  const int qr = lane & 15, lq = lane >> 4;
  const int rowBase = blockIdx.y * 128, colBase = blockIdx.x * 128;

  const int r0 = tid >> 3;        // 0..31
  const int k8 = (tid & 7) * 8;
  const unsigned short *pA[4], *pB[4];
#pragma unroll
  for (int j = 0; j < 4; ++j) {
    int rl = r0 + 32*j;
    int grow = rowBase + rl;
    int gi = (grow < cnt) ? grow : (cnt - 1);
    int arow = (EPI == 2) ? list[base + gi] : (base + gi);
    pA[j] = A + (size_t)arow * 1024 + k8;
    pB[j] = Bp + (size_t)(colBase + rl) * 1024 + k8;
  }
  f32x4 acc[4][4];
#pragma unroll
  for (int m2 = 0; m2 < 4; ++m2)
#pragma unroll
    for (int n2 = 0; n2 < 4; ++n2) acc[m2][n2] = fzero4();

  uint4 sA[4], sB[4];
#pragma unroll
  for (int j = 0; j < 4; ++j) { sA[j] = *(const uint4*)pA[j]; sB[j] = *(const uint4*)pB[j]; }
  for (int kt = 0; kt < 16; ++kt) {
    __syncthreads();
#pragma unroll
    for (int j = 0; j < 4; ++j) {
      int rr = r0 + 32*j;
      *(uint4*)&As[rr][k8] = sA[j];
      *(uint4*)&Bs[rr][k8] = sB[j];
    }
    __syncthreads();
    if (kt + 1 < 16) {
      int off = (kt + 1) * 64;
#pragma unroll
      for (int j = 0; j < 4; ++j) {
        sA[j] = *(const uint4*)(pA[j] + off);
        sB[j] = *(const uint4*)(pB[j] + off);
      }
    }
    bf16x8 af[2][4], bf[2][4];
#pragma unroll
    for (int mt = 0; mt < 4; ++mt) {
      af[0][mt] = *(const bf16x8*)&As[wm*64 + mt*16 + qr][lq*8];
      af[1][mt] = *(const bf16x8*)&As[wm*64 + mt*16 + qr][32 + lq*8];
    }
#pragma unroll
    for (int nt = 0; nt < 4; ++nt) {
      bf[0][nt] = *(const bf16x8*)&Bs[wn*64 + nt*16 + qr][lq*8];
      bf[1][nt] = *(const bf16x8*)&Bs[wn*64 + nt*16 + qr][32 + lq*8];
    }
#pragma unroll
    for (int kc = 0; kc < 2; ++kc)
#pragma unroll
      for (int mt = 0; mt < 4; ++mt)
#pragma unroll
        for (int nt = 0; nt < 4; ++nt)
          acc[mt][nt] = __builtin_amdgcn_mfma_f32_16x16x32_bf16(
              af[kc][mt], bf[kc][nt], acc[mt][nt], 0, 0, 0);
  }
#pragma unroll
  for (int mt = 0; mt < 4; ++mt)
#pragma unroll
    for (int nt = 0; nt < 4; ++nt)
#pragma unroll
      for (int r = 0; r < 4; ++r) {
        int grow = rowBase + wm*64 + mt*16 + lq*4 + r;
        int col  = colBase + wn*64 + nt*16 + qr;
        if (grow < cnt) {
          float v = acc[mt][nt][r] + biasp[col];
          if (EPI == 2) {
            float ge = 0.5f * v * (1.0f + erff(v * 0.70710678118654752f));
            out_bf[(size_t)(base + grow) * 1024 + col] = f2bf(ge);
          } else {
            int n = list[base + grow];
            size_t o2 = (size_t)n * 1024 + col;
            out_f[o2] = v + res[o2];
          }
        }
      }
}

// ---------------------------------------------------------------------------
extern "C" void kernel_launch(void* const* d_in, const int* in_sizes, int n_in,
                              void* d_out, int out_size, void* d_ws, size_t ws_size,
                              hipStream_t stream) {
  const float* x   = (const float*)d_in[0];
  const float* ipw = (const float*)d_in[1];
  const float* ipb = (const float*)d_in[2];
  const float* ow  = (const float*)d_in[3];
  const float* ob  = (const float*)d_in[4];
  const float* g1  = (const float*)d_in[5];
  const float* b1n = (const float*)d_in[6];
  const float* rw  = (const float*)d_in[7];
  const float* rb  = (const float*)d_in[8];
  const float* w1  = (const float*)d_in[9];
  const float* b1e = (const float*)d_in[10];
  const float* w2  = (const float*)d_in[11];
  const float* b2e = (const float*)d_in[12];
  const float* g2  = (const float*)d_in[13];
  const float* b2n = (const float*)d_in[14];

  char* ws = (char*)d_ws;
  const size_t MB = 1048576;
  _Float16* Xh  = (_Float16*)(ws + 0*MB);
  _Float16* Xl  = (_Float16*)(ws + 16*MB);
  _Float16* Wih = (_Float16*)(ws + 32*MB);
  _Float16* Wil = (_Float16*)(ws + 38*MB);
  _Float16* Woh = (_Float16*)(ws + 44*MB);
  _Float16* Wol = (_Float16*)(ws + 46*MB);
  unsigned short* w1b = (unsigned short*)(ws + 48*MB);
  unsigned short* w2b = (unsigned short*)(ws + 64*MB);
  _Float16* Qh  = (_Float16*)(ws + 80*MB);
  _Float16* Ql  = (_Float16*)(ws + 96*MB);
  _Float16* Kh  = (_Float16*)(ws + 112*MB);
  _Float16* Kl  = (_Float16*)(ws + 128*MB);
  _Float16* Vth = (_Float16*)(ws + 144*MB);
  _Float16* Vtl = (_Float16*)(ws + 160*MB);
  // overlays of dead regions:
  _Float16* Ch  = Xh;                                     // ctx hi (X dead)
  _Float16* Cl  = Xl;                                     // ctx lo
  float* tmp    = (float*)(ws + 80*MB);                   // over Q (dead post-attn)
  float* hbuf   = (float*)(ws + 112*MB);                  // over K
  unsigned short* hbf = (unsigned short*)(ws + 144*MB);   // over Vth
  unsigned short* he  = (unsigned short*)(ws + 160*MB);   // over Vtl
  int* assign = (int*)(ws + 176*MB);
  int* list   = (int*)(ws + 176*MB + 32768);
  int* counts = (int*)(ws + 176*MB + 65536);

  // 1) precision-split / cast weights & activations
  split_kernel<<<8192, 256, 0, stream>>>(x,   Xh,  Xl,  2048.0f, 2097152);
  split_kernel<<<3072, 256, 0, stream>>>(ipw, Wih, Wil, 1024.0f, 786432);
  split_kernel<<<1024, 256, 0, stream>>>(ow,  Woh, Wol, 1024.0f, 262144);
  castbf_kernel<<<8192, 256, 0, stream>>>(w1, w1b, 2097152);
  castbf_kernel<<<8192, 256, 0, stream>>>(w2, w2b, 2097152);

  // 2) QKV projection (fp16x3), coalesced scatter epilogue
  gemm_f16x3<0><<<1536, 256, 0, stream>>>(
      Xh, Xl, Wih, Wil, ipb, 3072, 1024, nullptr, nullptr,
      Qh, Ql, Kh, Kl, Vth, Vtl);

  // 3) flash attention
  attn_f16x3<<<dim3(16, 128), 256, 0, stream>>>(Qh, Ql, Kh, Kl, Vth, Vtl, Ch, Cl);

  // 4) out-proj + residual(x) -> tmp
  gemm_f16x3<1><<<512, 256, 0, stream>>>(
      Ch, Cl, Woh, Wol, ob, 1024, 1024, tmp, x,
      nullptr, nullptr, nullptr, nullptr, nullptr, nullptr);

  // 5) LN1 -> h (fp32) + h_bf
  ln_kernel<<<8192, 256, 0, stream>>>(tmp, g1, b1n, hbuf, hbf, 1);

  // 6) router -> assign; bucket tokens per expert
  router_kernel<<<2048, 256, 0, stream>>>(hbuf, rw, rb, assign);
  zero_kernel<<<1, 64, 0, stream>>>(counts);
  count_kernel<<<32, 256, 0, stream>>>(assign, counts);
  scatter_kernel<<<32, 256, 0, stream>>>(assign, counts, list);

  // 7) MoE FFN (bf16): he = gelu(h@w1^T+b1) ; tmp = h + (he@w2^T+b2)
  gemm_moe<2><<<dim3(8, 64, 8), 256, 0, stream>>>(
      hbf, w1b, b1e, nullptr, nullptr, he, list, counts);
  gemm_moe<3><<<dim3(8, 64, 8), 256, 0, stream>>>(
      he, w2b, b2e, hbuf, tmp, nullptr, list, counts);

  // 8) LN2 -> d_out
  ln_kernel<<<8192, 256, 0, stream>>>(tmp, g2, b2n, (float*)d_out, nullptr, 0);
}

// Round 3
// 1079.386 us; speedup vs baseline: 1.4660x; 1.0776x over previous
//
#include <hip/hip_runtime.h>
#include <math.h>

// ---------------------------------------------------------------------------
// StandardMoELayer on MI355X.
// Precision: fp16x3 split-MFMA upstream of router (routing must match fp32
// reference); bf16 MFMA for post-router MoE FFN.
// R3: gemm_f16x3 double-buffered LDS pipeline (T3 2-phase); attn reg-staged
// K/V prefetch (T14) + per-XCD bh ownership + removed pre-PV barrier;
// epilogue V-scatter bank-conflict XOR swizzle.
// ---------------------------------------------------------------------------

typedef __attribute__((ext_vector_type(4))) float f32x4;
typedef __attribute__((ext_vector_type(8))) _Float16 f16x8;
typedef __attribute__((ext_vector_type(4))) _Float16 f16x4;
typedef __attribute__((ext_vector_type(8))) short bf16x8;

#define DEVI static __device__ __forceinline__

DEVI unsigned short f2bf(float f) {
  unsigned int u = __builtin_bit_cast(unsigned int, f);
  return (unsigned short)((u + 0x7fffu + ((u >> 16) & 1u)) >> 16);
}

DEVI f32x4 fzero4() { f32x4 z; z[0]=0.f; z[1]=0.f; z[2]=0.f; z[3]=0.f; return z; }

DEVI void splitf16(float v, _Float16* hi, _Float16* lo) {
  _Float16 h = (_Float16)v;
  *hi = h;
  *lo = (_Float16)(v - (float)h);
}

DEVI void gload16(const void* g, void* l) {
  __builtin_amdgcn_global_load_lds(
      (__attribute__((address_space(1))) void*)(g),
      (__attribute__((address_space(3))) void*)(l), 16, 0, 0);
}

// ---------------------------------------------------------------------------
// elementwise prep kernels
// ---------------------------------------------------------------------------
__global__ void split_kernel(const float* __restrict__ in,
                             _Float16* __restrict__ oh, _Float16* __restrict__ ol,
                             float scale, int n4) {
  int i = blockIdx.x * 256 + threadIdx.x;
  if (i >= n4) return;
  float4 v = ((const float4*)in)[i];
  f16x4 hv, lv; _Float16 hh, ll;
  splitf16(v.x * scale, &hh, &ll); hv[0]=hh; lv[0]=ll;
  splitf16(v.y * scale, &hh, &ll); hv[1]=hh; lv[1]=ll;
  splitf16(v.z * scale, &hh, &ll); hv[2]=hh; lv[2]=ll;
  splitf16(v.w * scale, &hh, &ll); hv[3]=hh; lv[3]=ll;
  ((f16x4*)oh)[i] = hv;
  ((f16x4*)ol)[i] = lv;
}

__global__ void castbf_kernel(const float* __restrict__ in,
                              unsigned short* __restrict__ o, int n4) {
  int i = blockIdx.x * 256 + threadIdx.x;
  if (i >= n4) return;
  float4 v = ((const float4*)in)[i];
  ushort4 r;
  r.x = f2bf(v.x); r.y = f2bf(v.y); r.z = f2bf(v.z); r.w = f2bf(v.w);
  ((ushort4*)o)[i] = r;
}

// ---------------------------------------------------------------------------
// fp16x3 GEMM: C[M=8192,N] = A[M,K] * W[N,K]^T  (A scaled 2^11, W scaled 2^10)
// 128x128 tile, BK=32, 4 waves. Double-buffered global_load_lds pipeline:
//   barrier -> issue gloads(t+1 -> buf^1) -> ds_read/MFMA(t from buf)
// XCD-chunked grid: each XCD owns N/8 col-panels (B L2-resident).
// EPI 0: +bias, LDS-restage, coalesced split-store Q/K ([bh][t][d]) and
//        V transposed ([bh][d][t]).  EPI 1: +bias +res -> fp32 out.
// ---------------------------------------------------------------------------
template<int EPI>
__global__ __launch_bounds__(256) void gemm_f16x3(
    const _Float16* __restrict__ Ah, const _Float16* __restrict__ Al,
    const _Float16* __restrict__ Bh, const _Float16* __restrict__ Bl,
    const float* __restrict__ bias, int N, int K,
    float* __restrict__ out_f, const float* __restrict__ res,
    _Float16* __restrict__ Qh, _Float16* __restrict__ Ql,
    _Float16* __restrict__ Kh, _Float16* __restrict__ Kl,
    _Float16* __restrict__ Vh, _Float16* __restrict__ Vl) {
  __shared__ __align__(16) char smem[65536];  // 2 x (4 arrays x 128 x 64 B)
  const int tid = threadIdx.x;
  const int lane = tid & 63, wave = tid >> 6;
  const int wm = wave >> 1, wn = wave & 1;
  const int qr = lane & 15, lq = lane >> 4;

  // XCD-chunked block remap (nwg % 8 == 0 here)
  const int xcd = blockIdx.x & 7, idx = blockIdx.x >> 3;
  const int colsPerX = (N >> 7) >> 3;
  const int rowb = idx / colsPerX;
  const int colb = xcd * colsPerX + (idx - rowb * colsPerX);
  const int rowBase = rowb * 128, colBase = colb * 128;

  // staging: granule-swizzled per-lane global source, linear LDS dest.
  const char* gsrc[8];
  unsigned ldso[8];
  {
    const int srow = (wave << 4) + (lane >> 2);  // 0..63 within 64-row half
    const int sg = lane & 3;
#pragma unroll
    for (int i = 0; i < 8; ++i) {
      int a = i >> 1, j = i & 1;
      int row = j * 64 + srow;
      int gs = sg ^ ((row >> 1) & 3);
      const _Float16* basep = (a == 0) ? Ah : (a == 1) ? Al : (a == 2) ? Bh : Bl;
      int R0 = (a < 2) ? rowBase : colBase;
      gsrc[i] = (const char*)(basep + (size_t)(R0 + row) * K) + gs * 16;
      ldso[i] = a * 8192 + j * 4096 + wave * 1024;  // wave-uniform
    }
  }

  f32x4 acc[4][4];
#pragma unroll
  for (int m = 0; m < 4; ++m)
#pragma unroll
    for (int n = 0; n < 4; ++n) acc[m][n] = fzero4();

  const int gfr = (qr >> 1) & 3;  // frag granule swizzle term
  const int NT = K >> 5;
  // prologue: stage tile 0 into buf 0
#pragma unroll
  for (int i = 0; i < 8; ++i) gload16(gsrc[i], smem + ldso[i]);
#pragma unroll
  for (int i = 0; i < 8; ++i) gsrc[i] += 64;

  for (int kt = 0; kt < NT; ++kt) {
    __syncthreads();  // drains own vmcnt -> tile kt resident in buf[kt&1]
    const int cur = (kt & 1) << 15;
    const int nxt = cur ^ 32768;
    if (kt + 1 < NT) {
#pragma unroll
      for (int i = 0; i < 8; ++i) gload16(gsrc[i], smem + nxt + ldso[i]);
#pragma unroll
      for (int i = 0; i < 8; ++i) gsrc[i] += 64;
    }
    f16x8 ahf[4], alf[4], bhf[4], blf[4];
#pragma unroll
    for (int mt = 0; mt < 4; ++mt) {
      int off = cur + (wm * 64 + mt * 16 + qr) * 64 + ((lq ^ gfr) * 16);
      ahf[mt] = *(const f16x8*)(smem + off);
      alf[mt] = *(const f16x8*)(smem + 8192 + off);
    }
#pragma unroll
    for (int nt = 0; nt < 4; ++nt) {
      int off = cur + (wn * 64 + nt * 16 + qr) * 64 + ((lq ^ gfr) * 16);
      bhf[nt] = *(const f16x8*)(smem + 16384 + off);
      blf[nt] = *(const f16x8*)(smem + 24576 + off);
    }
#pragma unroll
    for (int mt = 0; mt < 4; ++mt)
#pragma unroll
      for (int nt = 0; nt < 4; ++nt) {
        f32x4 c = acc[mt][nt];
        c = __builtin_amdgcn_mfma_f32_16x16x32_f16(ahf[mt], bhf[nt], c, 0, 0, 0);
        c = __builtin_amdgcn_mfma_f32_16x16x32_f16(ahf[mt], blf[nt], c, 0, 0, 0);
        c = __builtin_amdgcn_mfma_f32_16x16x32_f16(alf[mt], bhf[nt], c, 0, 0, 0);
        acc[mt][nt] = c;
      }
  }

  const float inv21 = 1.0f / 2097152.0f;  // 2^-21
  float biasv[4];
#pragma unroll
  for (int nt = 0; nt < 4; ++nt) biasv[nt] = bias[colBase + wn * 64 + nt * 16 + qr];

  if (EPI == 0) {
    __syncthreads();  // staging LDS (buf0) reusable now
    const int sect = colBase >> 10;                // 0=Q 1=K 2=V (block-uniform)
    const int hhBase = (colBase & 1023) >> 6;
    const int t0 = rowBase >> 3;
    _Float16* L = (_Float16*)smem;                 // 16384 fp16 = 32 KB
    _Float16* dstH = (sect == 0) ? Qh : (sect == 1) ? Kh : Vh;
    _Float16* dstL = (sect == 0) ? Ql : (sect == 1) ? Kl : Vl;
#pragma unroll
    for (int pass = 0; pass < 2; ++pass) {
      if (pass) __syncthreads();
      // scatter acc into LDS in output-linear layout
#pragma unroll
      for (int mt = 0; mt < 4; ++mt)
#pragma unroll
        for (int nt = 0; nt < 4; ++nt)
#pragma unroll
          for (int r = 0; r < 4; ++r) {
            int rl = wm * 64 + mt * 16 + lq * 4 + r;
            int cl = wn * 64 + nt * 16 + qr;
            float v = acc[mt][nt][r] * inv21 + biasv[nt];
            _Float16 h_, l_;
            splitf16(v * 2048.0f, &h_, &l_);
            int off;
            if (sect < 2)
              off = ((rl & 7) * 2 + (cl >> 6)) * 1024 + (rl >> 3) * 64 + (cl & 63);
            else  // granule XOR-swizzle: kills 16-way bank conflict
              off = (cl >> 6) * 8192 + (cl & 63) * 128 +
                    (((rl & 7) ^ (cl & 7)) * 16) + (rl >> 3);
            L[off] = pass ? l_ : h_;
          }
      __syncthreads();
      _Float16* dst = pass ? dstL : dstH;
      if (sect < 2) {
#pragma unroll
        for (int j = 0; j < 8; ++j) {
          int c = j * 256 + tid;                   // 16B chunk id, 0..2047
          int b = c >> 8, hh = (c >> 7) & 1;
          int tl = (c >> 3) & 15, dd = (c & 7) * 8;
          size_t gd = ((size_t)(b * 16 + hhBase + hh) << 16) +
                      (size_t)(t0 + tl) * 64 + dd;
          *(uint4*)(dst + gd) = *(const uint4*)(L + (size_t)c * 8);
        }
      } else {
#pragma unroll
        for (int j = 0; j < 4; ++j) {
          int c = j * 256 + tid;                   // 32B chunk id, 0..1023
          int hh = c >> 9, dd = (c >> 3) & 63, b = c & 7;
          size_t gd = ((size_t)(b * 16 + hhBase + hh) << 16) +
                      (size_t)dd * 1024 + t0;
          int gb = hh * 8192 + dd * 128 + ((b ^ (dd & 7)) * 16);
          *(uint4*)(dst + gd)     = *(const uint4*)(L + gb);
          *(uint4*)(dst + gd + 8) = *(const uint4*)(L + gb + 8);
        }
      }
    }
  } else {
#pragma unroll
    for (int mt = 0; mt < 4; ++mt)
#pragma unroll
      for (int nt = 0; nt < 4; ++nt)
#pragma unroll
        for (int r = 0; r < 4; ++r) {
          int grow = rowBase + wm * 64 + mt * 16 + lq * 4 + r;
          int col = colBase + wn * 64 + nt * 16 + qr;
          size_t o = (size_t)grow * N + col;
          out_f[o] = acc[mt][nt][r] * inv21 + biasv[nt] + res[o];
        }
  }
}

// ---------------------------------------------------------------------------
// flash attention, fp16x3. 2048 blocks, XCD-remapped so each XCD owns 16
// consecutive bh (K/V L2-resident). block: 256 = 4 waves x 16 q-rows.
// Q/K layout [bh][t][d] (scaled 2^11 split); V layout [bh][d][t].
// K/V reg-prefetch overlaps global latency with QK^T/softmax/PV.
// ---------------------------------------------------------------------------
__global__ __launch_bounds__(256) void attn_f16x3(
    const _Float16* __restrict__ Qh, const _Float16* __restrict__ Ql,
    const _Float16* __restrict__ Kh, const _Float16* __restrict__ Kl,
    const _Float16* __restrict__ Vth, const _Float16* __restrict__ Vtl,
    _Float16* __restrict__ Ch, _Float16* __restrict__ Cl) {
  __shared__ _Float16 KsH[64][72], KsL[64][72], VsH[64][72], VsL[64][72];
  __shared__ _Float16 PsH[4][16][72], PsL[4][16][72];
  const int tid = threadIdx.x;
  const int lane = tid & 63, wave = tid >> 6;
  const int qr = lane & 15, lq = lane >> 4;
  // XCD remap: lin%8 = XCD -> give each XCD a contiguous bh range.
  const int lin = blockIdx.y * 16 + blockIdx.x;
  const int xcd = lin & 7, k6 = lin >> 3;        // k6: 0..255
  const int bh = xcd * 16 + (k6 >> 4);
  const int qt = k6 & 15;
  const size_t bo = (size_t)bh * 65536;
  const _Float16* Qhp = Qh + bo; const _Float16* Qlp = Ql + bo;
  const _Float16* Khp = Kh + bo; const _Float16* Klp = Kl + bo;
  const _Float16* Vhp = Vth + bo; const _Float16* Vlp = Vtl + bo;
  const int q0 = qt * 64 + wave * 16;

  f16x8 qhf[2], qlf[2];
#pragma unroll
  for (int kc = 0; kc < 2; ++kc) {
    size_t qo = (size_t)(q0 + qr) * 64 + kc*32 + lq*8;
    qhf[kc] = *(const f16x8*)(Qhp + qo);
    qlf[kc] = *(const f16x8*)(Qlp + qo);
  }
  f32x4 o[4]; float m[4], l[4];
#pragma unroll
  for (int i = 0; i < 4; ++i) { o[i] = fzero4(); m[i] = -3.0e38f; l[i] = 0.f; }

  const int r0 = tid >> 3;        // 0..31
  const int k8 = (tid & 7) * 8;
  uint4 rKH[2], rKL[2], rVH[2], rVL[2];
#define ATTN_LOAD(kb_)                                                        \
  {                                                                           \
    _Pragma("unroll") for (int j = 0; j < 2; ++j) {                           \
      int rr = r0 + 32 * j;                                                   \
      rKH[j] = *(const uint4*)(Khp + (size_t)((kb_)*64 + rr) * 64 + k8);      \
      rKL[j] = *(const uint4*)(Klp + (size_t)((kb_)*64 + rr) * 64 + k8);      \
      rVH[j] = *(const uint4*)(Vhp + (size_t)rr * 1024 + (kb_)*64 + k8);      \
      rVL[j] = *(const uint4*)(Vlp + (size_t)rr * 1024 + (kb_)*64 + k8);      \
    }                                                                         \
  }
  ATTN_LOAD(0)
  for (int kb = 0; kb < 16; ++kb) {
    __syncthreads();                 // prev PV done reading LDS
#pragma unroll
    for (int j = 0; j < 2; ++j) {
      int rr = r0 + 32*j;
      *(uint4*)&KsH[rr][k8] = rKH[j];
      *(uint4*)&KsL[rr][k8] = rKL[j];
      *(uint4*)&VsH[rr][k8] = rVH[j];
      *(uint4*)&VsL[rr][k8] = rVL[j];
    }
    __syncthreads();                 // publish tile kb
    if (kb + 1 < 16) ATTN_LOAD(kb + 1)   // overlaps all compute below
    f32x4 s[4];
#pragma unroll
    for (int nt = 0; nt < 4; ++nt) {
      f32x4 z = fzero4();
#pragma unroll
      for (int kc = 0; kc < 2; ++kc) {
        f16x8 kh_ = *(const f16x8*)&KsH[nt*16 + qr][kc*32 + lq*8];
        f16x8 kl_ = *(const f16x8*)&KsL[nt*16 + qr][kc*32 + lq*8];
        z = __builtin_amdgcn_mfma_f32_16x16x32_f16(qhf[kc], kh_, z, 0, 0, 0);
        z = __builtin_amdgcn_mfma_f32_16x16x32_f16(qhf[kc], kl_, z, 0, 0, 0);
        z = __builtin_amdgcn_mfma_f32_16x16x32_f16(qlf[kc], kh_, z, 0, 0, 0);
      }
      s[nt] = z;
    }
    const float sscale = 2.9802322387695312e-08f;  // 2^-22 * 0.125
#pragma unroll
    for (int r = 0; r < 4; ++r) {
#pragma unroll
      for (int nt = 0; nt < 4; ++nt) s[nt][r] *= sscale;
      float mx = fmaxf(fmaxf(s[0][r], s[1][r]), fmaxf(s[2][r], s[3][r]));
      mx = fmaxf(mx, __shfl_xor(mx, 1, 16));
      mx = fmaxf(mx, __shfl_xor(mx, 2, 16));
      mx = fmaxf(mx, __shfl_xor(mx, 4, 16));
      mx = fmaxf(mx, __shfl_xor(mx, 8, 16));
      float mn = fmaxf(m[r], mx);
      float al = __expf(m[r] - mn);
      m[r] = mn;
      float rs = 0.f;
#pragma unroll
      for (int nt = 0; nt < 4; ++nt) {
        float p = __expf(s[nt][r] - mn);
        s[nt][r] = p;
        rs += p;
      }
      rs += __shfl_xor(rs, 1, 16);
      rs += __shfl_xor(rs, 2, 16);
      rs += __shfl_xor(rs, 4, 16);
      rs += __shfl_xor(rs, 8, 16);
      l[r] = l[r] * al + rs;
#pragma unroll
      for (int dt = 0; dt < 4; ++dt) o[dt][r] *= al;
    }
#pragma unroll
    for (int nt = 0; nt < 4; ++nt)
#pragma unroll
      for (int r = 0; r < 4; ++r) {
        _Float16 ph, pl;
        splitf16(s[nt][r] * 2048.0f, &ph, &pl);
        PsH[wave][lq*4 + r][nt*16 + qr] = ph;
        PsL[wave][lq*4 + r][nt*16 + qr] = pl;
      }
    // Ps is per-wave: no cross-wave barrier needed, just LDS-order fence.
    asm volatile("s_waitcnt lgkmcnt(0)" ::: "memory");
    __builtin_amdgcn_sched_barrier(0);
#pragma unroll
    for (int kc = 0; kc < 2; ++kc) {
      f16x8 pah = *(const f16x8*)&PsH[wave][qr][kc*32 + lq*8];
      f16x8 pal = *(const f16x8*)&PsL[wave][qr][kc*32 + lq*8];
#pragma unroll
      for (int dt = 0; dt < 4; ++dt) {
        f16x8 vh_ = *(const f16x8*)&VsH[dt*16 + qr][kc*32 + lq*8];
        f16x8 vl_ = *(const f16x8*)&VsL[dt*16 + qr][kc*32 + lq*8];
        o[dt] = __builtin_amdgcn_mfma_f32_16x16x32_f16(pah, vh_, o[dt], 0, 0, 0);
        o[dt] = __builtin_amdgcn_mfma_f32_16x16x32_f16(pah, vl_, o[dt], 0, 0, 0);
        o[dt] = __builtin_amdgcn_mfma_f32_16x16x32_f16(pal, vh_, o[dt], 0, 0, 0);
      }
    }
  }
#undef ATTN_LOAD
  const int b = bh >> 4, hh = bh & 15;
  const float inv22 = 1.0f / 4194304.0f;  // 2^-22
#pragma unroll
  for (int dt = 0; dt < 4; ++dt)
#pragma unroll
    for (int r = 0; r < 4; ++r) {
      int tq = q0 + lq*4 + r;
      float v = o[dt][r] * inv22 / l[r];
      size_t idx = ((size_t)tq * 8 + b) * 1024 + hh*64 + dt*16 + qr;
      _Float16 h_, l_;
      splitf16(v * 2048.0f, &h_, &l_);
      Ch[idx] = h_; Cl[idx] = l_;
    }
}

// ---------------------------------------------------------------------------
// LayerNorm over C=1024. one block per row.
// ---------------------------------------------------------------------------
__global__ __launch_bounds__(256) void ln_kernel(
    const float* __restrict__ in, const float* __restrict__ g,
    const float* __restrict__ b, float* __restrict__ outf,
    unsigned short* __restrict__ outbf, int write_bf) {
  int row = blockIdx.x, tid = threadIdx.x;
  const float* xr = in + (size_t)row * 1024;
  float4 v = *(const float4*)(xr + tid*4);
  float s  = v.x + v.y + v.z + v.w;
  float sq = v.x*v.x + v.y*v.y + v.z*v.z + v.w*v.w;
#pragma unroll
  for (int off = 1; off < 64; off <<= 1) {
    s  += __shfl_xor(s, off, 64);
    sq += __shfl_xor(sq, off, 64);
  }
  __shared__ float red[8];
  int wv = tid >> 6, ln = tid & 63;
  if (ln == 0) { red[wv] = s; red[4 + wv] = sq; }
  __syncthreads();
  s  = red[0] + red[1] + red[2] + red[3];
  sq = red[4] + red[5] + red[6] + red[7];
  float mu   = s * 0.0009765625f;
  float var  = sq * 0.0009765625f - mu * mu;
  float rstd = 1.0f / sqrtf(var + 1e-5f);
  float4 gv = *(const float4*)(g + tid*4);
  float4 bv = *(const float4*)(b + tid*4);
  float4 o;
  o.x = (v.x - mu) * rstd * gv.x + bv.x;
  o.y = (v.y - mu) * rstd * gv.y + bv.y;
  o.z = (v.z - mu) * rstd * gv.z + bv.z;
  o.w = (v.w - mu) * rstd * gv.w + bv.w;
  *(float4*)(outf + (size_t)row * 1024 + tid*4) = o;
  if (write_bf) {
    ushort4 ob;
    ob.x = f2bf(o.x); ob.y = f2bf(o.y); ob.z = f2bf(o.z); ob.w = f2bf(o.w);
    *(ushort4*)(outbf + (size_t)row * 1024 + tid*4) = ob;
  }
}

// ---------------------------------------------------------------------------
// router: fp32 logits, top-2, assign = max(top2 indices). one wave per token.
// ---------------------------------------------------------------------------
__global__ __launch_bounds__(256) void router_kernel(
    const float* __restrict__ h, const float* __restrict__ rw,
    const float* __restrict__ rb, int* __restrict__ assign) {
  int tok = blockIdx.x * 4 + (threadIdx.x >> 6);
  int lane = threadIdx.x & 63;
  const float* hr = h + (size_t)tok * 1024;
  float acc[8];
#pragma unroll
  for (int e = 0; e < 8; ++e) acc[e] = 0.f;
#pragma unroll
  for (int j = 0; j < 4; ++j) {
    float4 hv = *(const float4*)(hr + lane*4 + j*256);
#pragma unroll
    for (int e = 0; e < 8; ++e) {
      float4 wv = *(const float4*)(rw + e*1024 + lane*4 + j*256);
      acc[e] += hv.x*wv.x + hv.y*wv.y + hv.z*wv.z + hv.w*wv.w;
    }
  }
#pragma unroll
  for (int e = 0; e < 8; ++e) {
#pragma unroll
    for (int off = 1; off < 64; off <<= 1) acc[e] += __shfl_xor(acc[e], off, 64);
    acc[e] += rb[e];
  }
  if (lane == 0) {
    int i1 = 0; float v1 = acc[0];
#pragma unroll
    for (int e = 1; e < 8; ++e) if (acc[e] > v1) { v1 = acc[e]; i1 = e; }
    int i2 = -1; float v2 = -3.0e38f;
#pragma unroll
    for (int e = 0; e < 8; ++e) if (e != i1 && acc[e] > v2) { v2 = acc[e]; i2 = e; }
    assign[tok] = (i1 > i2) ? i1 : i2;
  }
}

// ---------------------------------------------------------------------------
// expert bucketing
// ---------------------------------------------------------------------------
__global__ void zero_kernel(int* __restrict__ counts) {
  if (threadIdx.x < 16) counts[threadIdx.x] = 0;
}
__global__ void count_kernel(const int* __restrict__ assign, int* __restrict__ counts) {
  int i = blockIdx.x * 256 + threadIdx.x;
  if (i < 8192) atomicAdd(&counts[assign[i]], 1);
}
__global__ void scatter_kernel(const int* __restrict__ assign, int* __restrict__ counts,
                               int* __restrict__ list) {
  int i = blockIdx.x * 256 + threadIdx.x;
  if (i >= 8192) return;
  int a = assign[i];
  int base = 0;
  for (int e = 0; e < a; ++e) base += counts[e];
  int pos = atomicAdd(&counts[8 + a], 1);
  list[base + pos] = i;
}

// ---------------------------------------------------------------------------
// grouped MoE GEMM, bf16. grid (8, 64, E). 128x128 tile, BK=64.
// ---------------------------------------------------------------------------
template<int EPI>
__global__ __launch_bounds__(256) void gemm_moe(
    const unsigned short* __restrict__ A, const unsigned short* __restrict__ Bw,
    const float* __restrict__ bias, const float* __restrict__ res,
    float* __restrict__ out_f, unsigned short* __restrict__ out_bf,
    const int* __restrict__ list, const int* __restrict__ counts) {
  const int e = blockIdx.z;
  const int cnt = counts[e];
  if ((int)blockIdx.y * 128 >= cnt) return;
  int base = 0;
  for (int i = 0; i < 8; ++i) if (i < e) base += counts[i];
  const unsigned short* Bp = Bw + (size_t)e * 1048576;
  const float* biasp = bias + e * 1024;

  __shared__ unsigned short As[128][72], Bs[128][72];
  const int tid = threadIdx.x;
  const int lane = tid & 63, wave = tid >> 6;
  const int wm = wave >> 1, wn = wave & 1;
  const int qr = lane & 15, lq = lane >> 4;
  const int rowBase = blockIdx.y * 128, colBase = blockIdx.x * 128;

  const int r0 = tid >> 3;        // 0..31
  const int k8 = (tid & 7) * 8;
  const unsigned short *pA[4], *pB[4];
#pragma unroll
  for (int j = 0; j < 4; ++j) {
    int rl = r0 + 32*j;
    int grow = rowBase + rl;
    int gi = (grow < cnt) ? grow : (cnt - 1);
    int arow = (EPI == 2) ? list[base + gi] : (base + gi);
    pA[j] = A + (size_t)arow * 1024 + k8;
    pB[j] = Bp + (size_t)(colBase + rl) * 1024 + k8;
  }
  f32x4 acc[4][4];
#pragma unroll
  for (int m2 = 0; m2 < 4; ++m2)
#pragma unroll
    for (int n2 = 0; n2 < 4; ++n2) acc[m2][n2] = fzero4();

  uint4 sA[4], sB[4];
#pragma unroll
  for (int j = 0; j < 4; ++j) { sA[j] = *(const uint4*)pA[j]; sB[j] = *(const uint4*)pB[j]; }
  for (int kt = 0; kt < 16; ++kt) {
    __syncthreads();
#pragma unroll
    for (int j = 0; j < 4; ++j) {
      int rr = r0 + 32*j;
      *(uint4*)&As[rr][k8] = sA[j];
      *(uint4*)&Bs[rr][k8] = sB[j];
    }
    __syncthreads();
    if (kt + 1 < 16) {
      int off = (kt + 1) * 64;
#pragma unroll
      for (int j = 0; j < 4; ++j) {
        sA[j] = *(const uint4*)(pA[j] + off);
        sB[j] = *(const uint4*)(pB[j] + off);
      }
    }
    bf16x8 af[2][4], bf[2][4];
#pragma unroll
    for (int mt = 0; mt < 4; ++mt) {
      af[0][mt] = *(const bf16x8*)&As[wm*64 + mt*16 + qr][lq*8];
      af[1][mt] = *(const bf16x8*)&As[wm*64 + mt*16 + qr][32 + lq*8];
    }
#pragma unroll
    for (int nt = 0; nt < 4; ++nt) {
      bf[0][nt] = *(const bf16x8*)&Bs[wn*64 + nt*16 + qr][lq*8];
      bf[1][nt] = *(const bf16x8*)&Bs[wn*64 + nt*16 + qr][32 + lq*8];
    }
#pragma unroll
    for (int kc = 0; kc < 2; ++kc)
#pragma unroll
      for (int mt = 0; mt < 4; ++mt)
#pragma unroll
        for (int nt = 0; nt < 4; ++nt)
          acc[mt][nt] = __builtin_amdgcn_mfma_f32_16x16x32_bf16(
              af[kc][mt], bf[kc][nt], acc[mt][nt], 0, 0, 0);
  }
#pragma unroll
  for (int mt = 0; mt < 4; ++mt)
#pragma unroll
    for (int nt = 0; nt < 4; ++nt)
#pragma unroll
      for (int r = 0; r < 4; ++r) {
        int grow = rowBase + wm*64 + mt*16 + lq*4 + r;
        int col  = colBase + wn*64 + nt*16 + qr;
        if (grow < cnt) {
          float v = acc[mt][nt][r] + biasp[col];
          if (EPI == 2) {
            float ge = 0.5f * v * (1.0f + erff(v * 0.70710678118654752f));
            out_bf[(size_t)(base + grow) * 1024 + col] = f2bf(ge);
          } else {
            int n = list[base + grow];
            size_t o2 = (size_t)n * 1024 + col;
            out_f[o2] = v + res[o2];
          }
        }
      }
}

// ---------------------------------------------------------------------------
extern "C" void kernel_launch(void* const* d_in, const int* in_sizes, int n_in,
                              void* d_out, int out_size, void* d_ws, size_t ws_size,
                              hipStream_t stream) {
  const float* x   = (const float*)d_in[0];
  const float* ipw = (const float*)d_in[1];
  const float* ipb = (const float*)d_in[2];
  const float* ow  = (const float*)d_in[3];
  const float* ob  = (const float*)d_in[4];
  const float* g1  = (const float*)d_in[5];
  const float* b1n = (const float*)d_in[6];
  const float* rw  = (const float*)d_in[7];
  const float* rb  = (const float*)d_in[8];
  const float* w1  = (const float*)d_in[9];
  const float* b1e = (const float*)d_in[10];
  const float* w2  = (const float*)d_in[11];
  const float* b2e = (const float*)d_in[12];
  const float* g2  = (const float*)d_in[13];
  const float* b2n = (const float*)d_in[14];

  char* ws = (char*)d_ws;
  const size_t MB = 1048576;
  _Float16* Xh  = (_Float16*)(ws + 0*MB);
  _Float16* Xl  = (_Float16*)(ws + 16*MB);
  _Float16* Wih = (_Float16*)(ws + 32*MB);
  _Float16* Wil = (_Float16*)(ws + 38*MB);
  _Float16* Woh = (_Float16*)(ws + 44*MB);
  _Float16* Wol = (_Float16*)(ws + 46*MB);
  unsigned short* w1b = (unsigned short*)(ws + 48*MB);
  unsigned short* w2b = (unsigned short*)(ws + 64*MB);
  _Float16* Qh  = (_Float16*)(ws + 80*MB);
  _Float16* Ql  = (_Float16*)(ws + 96*MB);
  _Float16* Kh  = (_Float16*)(ws + 112*MB);
  _Float16* Kl  = (_Float16*)(ws + 128*MB);
  _Float16* Vth = (_Float16*)(ws + 144*MB);
  _Float16* Vtl = (_Float16*)(ws + 160*MB);
  // overlays of dead regions:
  _Float16* Ch  = Xh;                                     // ctx hi (X dead)
  _Float16* Cl  = Xl;                                     // ctx lo
  float* tmp    = (float*)(ws + 80*MB);                   // over Q (dead post-attn)
  float* hbuf   = (float*)(ws + 112*MB);                  // over K
  unsigned short* hbf = (unsigned short*)(ws + 144*MB);   // over Vth
  unsigned short* he  = (unsigned short*)(ws + 160*MB);   // over Vtl
  int* assign = (int*)(ws + 176*MB);
  int* list   = (int*)(ws + 176*MB + 32768);
  int* counts = (int*)(ws + 176*MB + 65536);

  // 1) precision-split / cast weights & activations
  split_kernel<<<8192, 256, 0, stream>>>(x,   Xh,  Xl,  2048.0f, 2097152);
  split_kernel<<<3072, 256, 0, stream>>>(ipw, Wih, Wil, 1024.0f, 786432);
  split_kernel<<<1024, 256, 0, stream>>>(ow,  Woh, Wol, 1024.0f, 262144);
  castbf_kernel<<<8192, 256, 0, stream>>>(w1, w1b, 2097152);
  castbf_kernel<<<8192, 256, 0, stream>>>(w2, w2b, 2097152);

  // 2) QKV projection (fp16x3), coalesced scatter epilogue
  gemm_f16x3<0><<<1536, 256, 0, stream>>>(
      Xh, Xl, Wih, Wil, ipb, 3072, 1024, nullptr, nullptr,
      Qh, Ql, Kh, Kl, Vth, Vtl);

  // 3) flash attention
  attn_f16x3<<<dim3(16, 128), 256, 0, stream>>>(Qh, Ql, Kh, Kl, Vth, Vtl, Ch, Cl);

  // 4) out-proj + residual(x) -> tmp
  gemm_f16x3<1><<<512, 256, 0, stream>>>(
      Ch, Cl, Woh, Wol, ob, 1024, 1024, tmp, x,
      nullptr, nullptr, nullptr, nullptr, nullptr, nullptr);

  // 5) LN1 -> h (fp32) + h_bf
  ln_kernel<<<8192, 256, 0, stream>>>(tmp, g1, b1n, hbuf, hbf, 1);

  // 6) router -> assign; bucket tokens per expert
  router_kernel<<<2048, 256, 0, stream>>>(hbuf, rw, rb, assign);
  zero_kernel<<<1, 64, 0, stream>>>(counts);
  count_kernel<<<32, 256, 0, stream>>>(assign, counts);
  scatter_kernel<<<32, 256, 0, stream>>>(assign, counts, list);

  // 7) MoE FFN (bf16): he = gelu(h@w1^T+b1) ; tmp = h + (he@w2^T+b2)
  gemm_moe<2><<<dim3(8, 64, 8), 256, 0, stream>>>(
      hbf, w1b, b1e, nullptr, nullptr, he, list, counts);
  gemm_moe<3><<<dim3(8, 64, 8), 256, 0, stream>>>(
      he, w2b, b2e, hbuf, tmp, nullptr, list, counts);

  // 8) LN2 -> d_out
  ln_kernel<<<8192, 256, 0, stream>>>(tmp, g2, b2n, (float*)d_out, nullptr, 0);
}